// Round 1
// baseline (189.625 us; speedup 1.0000x reference)
//
#include <hip/hip_runtime.h>
#include <math.h>

// CIRNet: T=1048576 rows x 18 feats. Outputs concat: r_predicts[N], regs[N], dts[N], N = T-1.
// Sequential SDE recurrence parallelized via chunked Newton / waveform relaxation:
//   per-chunk forward pass + derivative product -> affine boundary-correction scan -> iterate.
#define T_TOTAL 1048576
#define NSTEPS  1048575      // T-1
#define FEAT    18
#define NP      1048576      // padded length for ws arrays
#define CHUNKS  8192
#define CLEN    128          // CHUNKS*CLEN = 1048576 >= NSTEPS (last chunk: 127 valid steps)

// ---------------- K1: per-step coefficients + regs/dts outputs ----------------
__global__ void prep_kernel(const float* __restrict__ trace,
                            const float* __restrict__ sW,
                            const float* __restrict__ sb,
                            const float* __restrict__ eW,
                            const float* __restrict__ kp,
                            const float* __restrict__ thp,
                            float* __restrict__ dt,
                            float* __restrict__ pp,
                            float* __restrict__ out)
{
    int n = blockIdx.x * blockDim.x + threadIdx.x;
    if (n >= NSTEPS) return;
    const float* row = trace + (long)n * FEAT;
    float d = row[FEAT] - row[0];          // t[n+1] - t[n]
    float sig = sb[0];
#pragma unroll
    for (int j = 0; j < 8; ++j) sig = fmaf(row[2 + j], sW[j], sig);
    float eps = 0.f;
#pragma unroll
    for (int j = 0; j < 8; ++j) eps = fmaf(row[10 + j], eW[j], eps);
    dt[n] = d;
    pp[n] = sig * eps;
    float k = kp[0], th = thp[0];
    out[NSTEPS + n]     = fmaf(-sig, sig, 2.f * k * th);  // regs
    out[2 * NSTEPS + n] = d;                               // dts
}

// ---------------- K2: chunk forward pass with derivative product ----------------
__global__ void chunk_pass(const float* __restrict__ dt,
                           const float* __restrict__ pp,
                           const float* __restrict__ starts,
                           int first_iter,
                           const float* __restrict__ trace,
                           const float* __restrict__ kp,
                           const float* __restrict__ thp,
                           float* __restrict__ E,
                           float* __restrict__ P,
                           float* __restrict__ s_used)
{
    int c = blockIdx.x * blockDim.x + threadIdx.x;
    float k = kp[0], th = thp[0];
    float r = first_iter ? trace[1] : starts[c];   // r0 = trace[0,1]
    s_used[c] = r;
    int nbase = c * CLEN;
    bool full = (nbase + CLEN <= NSTEPS);
    const float4* d4 = (const float4*)(dt + nbase);
    const float4* p4 = (const float4*)(pp + nbase);
    float Pr = 1.f;
    float4 dbuf0 = d4[0], pbuf0 = p4[0];
    float4 dbuf1 = d4[1], pbuf1 = p4[1];
#define STEP2(dd, pj, ofs) { \
        int n = nbase + (ofs); \
        if (full || n < NSTEPS) { \
            float u  = r * (dd); \
            float au = fabsf(u); \
            float qs = sqrtf(au); \
            float ode = fmaf(k * (th - r), (dd), r); \
            float a   = fmaf(-k, (dd), 1.f); \
            float inv = (au > 1e-30f) ? rsqrtf(au) : 0.f; \
            float grad = fmaf((pj), 0.5f * (dd) * copysignf(inv, r), a); \
            r  = fmaf((pj), qs, ode); \
            Pr *= grad; \
        } }
#pragma unroll 1
    for (int g = 0; g < CLEN / 4; g += 2) {
        float4 dA = dbuf0, qA = pbuf0;
        float4 dB = dbuf1, qB = pbuf1;
        if (g + 2 < CLEN / 4) { dbuf0 = d4[g + 2]; pbuf0 = p4[g + 2]; }
        if (g + 3 < CLEN / 4) { dbuf1 = d4[g + 3]; pbuf1 = p4[g + 3]; }
        STEP2(dA.x, qA.x, 4 * g + 0)
        STEP2(dA.y, qA.y, 4 * g + 1)
        STEP2(dA.z, qA.z, 4 * g + 2)
        STEP2(dA.w, qA.w, 4 * g + 3)
        STEP2(dB.x, qB.x, 4 * g + 4)
        STEP2(dB.y, qB.y, 4 * g + 5)
        STEP2(dB.z, qB.z, 4 * g + 6)
        STEP2(dB.w, qB.w, 4 * g + 7)
    }
#undef STEP2
    E[c] = r;
    P[c] = Pr;
}

// ---------------- K3: affine boundary-correction scan (one block) ----------------
// x_0 = r0; x_{c+1} = E_c + P_c*(x_c - s_used_c)  ==  A_c*x_c + B_c
__global__ void correct_scan(const float* __restrict__ E,
                             const float* __restrict__ P,
                             const float* __restrict__ s_used,
                             const float* __restrict__ trace,
                             float* __restrict__ s_new)
{
    __shared__ float sA[1024];
    __shared__ float sB[1024];
    int t = threadIdx.x;
    float A[8], B[8];
    float aggA = 1.f, aggB = 0.f;
    int base = t * 8;
#pragma unroll
    for (int j = 0; j < 8; ++j) {
        int c = base + j;
        float Ac = P[c];
        float Bc = fmaf(-Ac, s_used[c], E[c]);
        A[j] = Ac; B[j] = Bc;
        aggB = fmaf(Ac, aggB, Bc);   // compose: existing agg, then map c
        aggA = Ac * aggA;
    }
    sA[t] = aggA; sB[t] = aggB;
    __syncthreads();
    for (int d = 1; d < 1024; d <<= 1) {
        float pA = 1.f, pB = 0.f;
        if (t >= d) { pA = sA[t - d]; pB = sB[t - d]; }
        __syncthreads();
        if (t >= d) {
            float cA = sA[t], cB = sB[t];
            sA[t] = cA * pA;              // earlier (t-d) then later (t)
            sB[t] = fmaf(cA, pB, cB);
        }
        __syncthreads();
    }
    float r0 = trace[1];
    float x = (t == 0) ? r0 : fmaf(sA[t - 1], r0, sB[t - 1]);  // exclusive prefix applied to r0
#pragma unroll
    for (int j = 0; j < 8; ++j) {
        s_new[base + j] = x;
        x = fmaf(A[j], x, B[j]);
    }
}

// ---------------- K4: final chunk pass writing r_predicts ----------------
__global__ void final_pass(const float* __restrict__ dt,
                           const float* __restrict__ pp,
                           const float* __restrict__ starts,
                           const float* __restrict__ kp,
                           const float* __restrict__ thp,
                           float* __restrict__ out)
{
    int c = blockIdx.x * blockDim.x + threadIdx.x;
    float k = kp[0], th = thp[0];
    float r = starts[c];
    int nbase = c * CLEN;
    const float4* d4 = (const float4*)(dt + nbase);
    const float4* p4 = (const float4*)(pp + nbase);
    float4 dbuf0 = d4[0], pbuf0 = p4[0];
    float4 dbuf1 = d4[1], pbuf1 = p4[1];
#define FSTEP(dd, pj) { \
        float u  = r * (dd); \
        float qs = sqrtf(fabsf(u)); \
        r = fmaf((pj), qs, fmaf(k * (th - r), (dd), r)); }
#pragma unroll 1
    for (int g = 0; g < CLEN / 4; g += 2) {
        float4 dA = dbuf0, qA = pbuf0;
        float4 dB = dbuf1, qB = pbuf1;
        if (g + 2 < CLEN / 4) { dbuf0 = d4[g + 2]; pbuf0 = p4[g + 2]; }
        if (g + 3 < CLEN / 4) { dbuf1 = d4[g + 3]; pbuf1 = p4[g + 3]; }
        float4 ov;
        FSTEP(dA.x, qA.x) ov.x = r;
        FSTEP(dA.y, qA.y) ov.y = r;
        FSTEP(dA.z, qA.z) ov.z = r;
        FSTEP(dA.w, qA.w) ov.w = r;
        int n0 = nbase + 4 * g;
        if (n0 + 4 <= NSTEPS) {
            *(float4*)(out + n0) = ov;
        } else {
            if (n0 + 0 < NSTEPS) out[n0 + 0] = ov.x;
            if (n0 + 1 < NSTEPS) out[n0 + 1] = ov.y;
            if (n0 + 2 < NSTEPS) out[n0 + 2] = ov.z;
        }
        FSTEP(dB.x, qB.x) ov.x = r;
        FSTEP(dB.y, qB.y) ov.y = r;
        FSTEP(dB.z, qB.z) ov.z = r;
        FSTEP(dB.w, qB.w) ov.w = r;
        n0 += 4;
        if (n0 + 4 <= NSTEPS) {
            *(float4*)(out + n0) = ov;
        } else {
            if (n0 + 0 < NSTEPS) out[n0 + 0] = ov.x;
            if (n0 + 1 < NSTEPS) out[n0 + 1] = ov.y;
            if (n0 + 2 < NSTEPS) out[n0 + 2] = ov.z;
        }
    }
#undef FSTEP
}

extern "C" void kernel_launch(void* const* d_in, const int* in_sizes, int n_in,
                              void* d_out, int out_size, void* d_ws, size_t ws_size,
                              hipStream_t stream)
{
    const float* trace = (const float*)d_in[0];
    const float* sW    = (const float*)d_in[1];
    const float* sb    = (const float*)d_in[2];
    const float* eW    = (const float*)d_in[3];
    const float* kp    = (const float*)d_in[4];
    const float* thp   = (const float*)d_in[5];
    float* out = (float*)d_out;

    float* w      = (float*)d_ws;        // needs ~8.5 MB
    float* dt     = w;                   // NP floats
    float* pp     = w + NP;              // NP floats
    float* E      = w + 2 * NP;          // CHUNKS
    float* P      = E + CHUNKS;          // CHUNKS
    float* s_used = P + CHUNKS;          // CHUNKS
    float* s_new  = s_used + CHUNKS;     // CHUNKS

    prep_kernel<<<(NSTEPS + 255) / 256, 256, 0, stream>>>(trace, sW, sb, eW, kp, thp, dt, pp, out);

    // Newton iteration 1 (starts = r0 everywhere)
    chunk_pass<<<CHUNKS / 256, 256, 0, stream>>>(dt, pp, s_new, 1, trace, kp, thp, E, P, s_used);
    correct_scan<<<1, 1024, 0, stream>>>(E, P, s_used, trace, s_new);
    // Newton iteration 2
    chunk_pass<<<CHUNKS / 256, 256, 0, stream>>>(dt, pp, s_new, 0, trace, kp, thp, E, P, s_used);
    correct_scan<<<1, 1024, 0, stream>>>(E, P, s_used, trace, s_new);
    // Newton iteration 3 (safety margin)
    chunk_pass<<<CHUNKS / 256, 256, 0, stream>>>(dt, pp, s_new, 0, trace, kp, thp, E, P, s_used);
    correct_scan<<<1, 1024, 0, stream>>>(E, P, s_used, trace, s_new);

    final_pass<<<CHUNKS / 256, 256, 0, stream>>>(dt, pp, s_new, kp, thp, out);
}